// Round 18
// baseline (144.105 us; speedup 1.0000x reference)
//
#include <hip/hip_runtime.h>
#include <stdint.h>

// ---------- types ----------
typedef __attribute__((ext_vector_type(8)))  __bf16 bf16x8;
typedef __attribute__((ext_vector_type(4)))  __bf16 bf16x4;
typedef __attribute__((ext_vector_type(4)))  float  f32x4;
typedef __attribute__((ext_vector_type(16))) float  f32x16;
typedef __attribute__((ext_vector_type(4)))  int    i32x4;

#define DEV static __device__ __forceinline__

DEV float fast_exp2(float x) {
#if __has_builtin(__builtin_amdgcn_exp2f)
  return __builtin_amdgcn_exp2f(x);
#else
  return exp2f(x);
#endif
}

// pack two f32 -> one u32 of 2x bf16 (lo = a, hi = b), RNE via (__bf16) cast
DEV uint32_t pack_bf2(float a, float b) {
  __bf16 x = (__bf16)a, y = (__bf16)b;
  uint16_t xu = __builtin_bit_cast(uint16_t, x);
  uint16_t yu = __builtin_bit_cast(uint16_t, y);
  return (uint32_t)xu | ((uint32_t)yu << 16);
}

// async global->LDS, 16B per lane; LDS dest = wave-uniform base + lane*16
DEV void gload_lds16(const void* g, void* l) {
  __builtin_amdgcn_global_load_lds(
      (const __attribute__((address_space(1))) void*)(uintptr_t)(g),
      (__attribute__((address_space(3))) void*)(uint32_t)(uintptr_t)(l),
      16, 0, 0);
}

// softmax scale folded into Q at GEMM0 epilogue: C = log2(e)/8
#define SM_SCALE 0.18033688f

// Fragment layout (for a row-major [R][K] bf16 operand, MFMA 16x16x32):
//   element (r,k) -> block ((r>>4)*(K/32) + (k>>5)), lane (r&15)+16*((k>>3)&3),
//   byte-in-lane (k&7)*2.  Block = 64 lanes x 16B = 1KB.  A gemm fragment
//   load is then exactly  base + lane*16  (coalesced dwordx4).

// ---------- fused prep ----------
// z in [0,3): Wq/Wk/Wv -> FRAGMENT-packed wf (concatenated [3072][1024])
// z == 3   : Wo -> row-major transposed wot (for gemm1, unchanged)
// z >= 4   : x fp32 -> FRAGMENT-packed xf
__global__ void k_prep(const float* __restrict__ x,  __bf16* __restrict__ xf,
                       const float* __restrict__ Wq, const float* __restrict__ Wk,
                       const float* __restrict__ Wv, const float* __restrict__ Wo,
                       __bf16* __restrict__ wf, __bf16* __restrict__ wot) {
  const int z = blockIdx.z;
  if (z < 4) {
    const float* W = (z == 0) ? Wq : (z == 1) ? Wk : (z == 2) ? Wv : Wo;
    __shared__ __bf16 T[64][66];
    int t = threadIdx.x;
    int r = t >> 2;            // 0..63
    int cq = (t & 3) << 4;     // 0,16,32,48
    {
      int gk = blockIdx.y * 64 + r;
      int gn0 = blockIdx.x * 64 + cq;
      const float* src = W + (size_t)gk * 1024 + gn0;
#pragma unroll
      for (int j = 0; j < 16; j += 4) {
        f32x4 v = *(const f32x4*)(src + j);
#pragma unroll
        for (int jj = 0; jj < 4; ++jj) T[r][cq + j + jj] = (__bf16)v[jj];
      }
    }
    __syncthreads();
    int gn = blockIdx.x * 64 + r;        // output row (n), k = by*64+cq..+15
    bf16x8 o0, o1;
#pragma unroll
    for (int j = 0; j < 8; ++j) { o0[j] = T[cq + j][r]; o1[j] = T[cq + 8 + j][r]; }
    if (z == 3) {
      __bf16* dst = wot + (size_t)gn * 1024 + blockIdx.y * 64 + cq;
      *(bf16x8*)dst = o0;
      *(bf16x8*)(dst + 8) = o1;
    } else {
      int nb = z * 64 + (gn >> 4);                    // global (nrow>>4)
      int kb = blockIdx.y * 2 + (cq >= 32);           // k 32-block (same for o0/o1)
      int lane0 = (gn & 15) + 16 * ((cq >> 3) & 3);
      int lane1 = (gn & 15) + 16 * (((cq + 8) >> 3) & 3);
      __bf16* blk = wf + ((size_t)nb * 32 + kb) * 512;
      *(bf16x8*)(blk + lane0 * 8) = o0;
      *(bf16x8*)(blk + lane1 * 8) = o1;
    }
  } else {
    // x -> xf fragments: each thread converts 8 consecutive k of one row
    int lb = (z - 4) * 256 + blockIdx.y * 16 + blockIdx.x;   // [0,2048)
    int e = (lb * 256 + (int)threadIdx.x) * 8;
    int m = e >> 10, k = e & 1023;
    const float* src = x + (size_t)m * 1024 + k;
    f32x4 v0 = *(const f32x4*)(src);
    f32x4 v1 = *(const f32x4*)(src + 4);
    bf16x8 o;
#pragma unroll
    for (int j = 0; j < 4; ++j) { o[j] = (__bf16)v0[j]; o[4 + j] = (__bf16)v1[j]; }
    *(bf16x8*)(xf + ((size_t)(m >> 4) * 32 + (k >> 5)) * 512 +
               ((m & 15) + 16 * ((k >> 3) & 3)) * 8) = o;
  }
}

// ---------- build V fragments only (K fragments come from gemm0) ----------
__global__ void k_vt(const __bf16* __restrict__ qkv, __bf16* __restrict__ kvf) {
  int lt = blockIdx.x, bh = blockIdx.y;
  int b = bh >> 4, h = bh & 15;
  int t = threadIdx.x;
  int lane = t & 63, slot = t >> 6;          // slot 0..3
  int l31 = lane & 31, hi = lane >> 5;

  __shared__ __bf16 T[64][66];   // T[kv_local][d]
  {
    int r = t >> 2, cq = (t & 3) << 4;
    const __bf16* src = qkv + (size_t)(b * 2048 + lt * 64 + r) * 3072 + 2048 + h * 64 + cq;
    bf16x8 v0 = *(const bf16x8*)src;
    bf16x8 v1 = *(const bf16x8*)(src + 8);
#pragma unroll
    for (int j = 0; j < 8; ++j) { T[r][cq + j] = v0[j]; T[r][cq + 8 + j] = v1[j]; }
  }
  __syncthreads();
#pragma unroll
  for (int tt = 0; tt < 2; ++tt) {
    bf16x8 val;
#pragma unroll
    for (int j = 0; j < 8; ++j)
      val[j] = T[tt * 32 + ((slot >> 1) * 2 + hi) * 8 + j][(slot & 1) * 32 + l31];
    __bf16* dst = kvf + (size_t)(bh * 64 + lt * 2 + tt) * 4096 + 2048 + slot * 512 + lane * 8;
    *(bf16x8*)dst = val;
  }
}

// ---------- GEMM0: fragment-direct, barrier-free, zero LDS ----------
// 128x128 tile, 4 waves (2x2), XCD-swizzled linear grid 768. Per K-step:
// 16 coalesced fragment loads (base + lane*16) + 32 MFMAs, software-pipelined
// one K-step ahead. K-column blocks (bn 8..16) write kvf K-fragments directly;
// Q blocks write row-major qkv * SM_SCALE; V blocks write row-major qkv.
__global__ void __launch_bounds__(256, 2)
k_gemm0(const __bf16* __restrict__ xf, const __bf16* __restrict__ wf,
        __bf16* __restrict__ Cout, __bf16* __restrict__ kvf,
        const float* __restrict__ b0, const float* __restrict__ b1,
        const float* __restrict__ b2) {
  const int t = threadIdx.x, wid = t >> 6, lane = t & 63;
  const int f = blockIdx.x;
  const int xcd = f & 7, i = f >> 3;            // i in [0,96)
  const int bm = (xcd & 3) * 8 + (i & 7);       // [0,32)
  const int bn = (xcd >> 2) * 12 + (i >> 3);    // [0,24)
  const int wm = wid >> 1, wn = wid & 1;
  const int l15 = lane & 15, l4 = lane >> 4;

  // fragment bases: row-block stride 32KB (32 k-blocks x 1KB)
  const char* abase = (const char*)xf + (size_t)(bm * 8 + wm * 4) * 32768 + lane * 16;
  const char* bbase = (const char*)wf + (size_t)(bn * 8 + wn * 4) * 32768 + lane * 16;

  f32x4 acc[4][4] = {};
  bf16x8 aA[8], bA[8], aB[8], bB[8];   // [kk*4 + ms/ns]

  auto LOADF = [&](bf16x8* af, bf16x8* bf, int kt) {
#pragma unroll
    for (int kk = 0; kk < 2; ++kk)
#pragma unroll
      for (int s = 0; s < 4; ++s) {
        af[kk * 4 + s] = *(const bf16x8*)(abase + s * 32768 + (kt * 2 + kk) * 1024);
        bf[kk * 4 + s] = *(const bf16x8*)(bbase + s * 32768 + (kt * 2 + kk) * 1024);
      }
  };
  auto STEP = [&](const bf16x8* af, const bf16x8* bf) {
#pragma unroll
    for (int kk = 0; kk < 2; ++kk)
#pragma unroll
      for (int ms = 0; ms < 4; ++ms)
#pragma unroll
        for (int ns = 0; ns < 4; ++ns)
          acc[ms][ns] = __builtin_amdgcn_mfma_f32_16x16x32_bf16(
              af[kk * 4 + ms], bf[kk * 4 + ns], acc[ms][ns], 0, 0, 0);
  };

  LOADF(aA, bA, 0);
  for (int kt = 0; kt < 16; kt += 2) {
    LOADF(aB, bB, kt + 1);
    STEP(aA, bA);
    if (kt + 2 < 16) LOADF(aA, bA, kt + 2);
    STEP(aB, bB);
  }

  const bool kblock = (bn >= 8 && bn < 16);
#pragma unroll
  for (int ms = 0; ms < 4; ++ms) {
#pragma unroll
    for (int ns = 0; ns < 4; ++ns) {
      int n = bn * 128 + wn * 64 + ns * 16 + l15;
      const float* bp = (n < 1024) ? b0 : ((n < 2048) ? b1 : b2);
      float bias = bp[n & 1023];
#pragma unroll
      for (int i2 = 0; i2 < 4; ++i2) {
        int m = bm * 128 + wm * 64 + ms * 16 + l4 * 4 + i2;
        float v = acc[ms][ns][i2] + bias;
        if (kblock) {
          // K fragment write (replaces qkv K region + copy pass)
          int dfull = n - 1024;
          int h = dfull >> 6, d = dfull & 63;
          int bb = m >> 11, mr = m & 2047;
          int tile = mr >> 5, r32 = mr & 31;
          int lanep = r32 + ((d >> 3) & 1) * 32;
          kvf[(size_t)((bb * 16 + h) * 64 + tile) * 4096 +
              (d >> 4) * 512 + lanep * 8 + (d & 7)] = (__bf16)v;
        } else {
          if (n < 1024) v *= SM_SCALE;   // fold softmax scale into Q
          Cout[(size_t)m * 3072 + n] = (__bf16)v;
        }
      }
    }
  }
}

// ---------- GEMM1: 128x64 tile, 4 waves of 64x32 (unchanged) ----------
__global__ void k_gemm1(const __bf16* __restrict__ A, const __bf16* __restrict__ Bt,
                        float* __restrict__ Cout, int M, int N, int K,
                        const float* __restrict__ b0) {
  __shared__ __align__(16) __bf16 As[128 * 64];  // 16 KB
  __shared__ __align__(16) __bf16 Bs[64 * 64];   // 8 KB
  const int t = threadIdx.x, wid = t >> 6, lane = t & 63;
  const int bm = blockIdx.y, bn = blockIdx.x;
  const int wm = wid >> 1, wn = wid & 1;
  const int l15 = lane & 15, l4 = lane >> 4;
  const int rr = lane >> 3, cc = lane & 7;
  f32x4 acc[4][2] = {};
  const int nk = K >> 6;
  for (int kt = 0; kt < nk; ++kt) {
    __syncthreads();
#pragma unroll
    for (int j = 0; j < 4; ++j) {
      int row = wid * 32 + j * 8 + rr;
      int csrc = (cc ^ (row & 7)) * 8;
      gload_lds16(A + (size_t)(bm * 128 + row) * K + kt * 64 + csrc,
                  (char*)As + (wid * 32 + j * 8) * 128);
    }
#pragma unroll
    for (int j = 0; j < 2; ++j) {
      int row = wid * 16 + j * 8 + rr;
      int csrc = (cc ^ (row & 7)) * 8;
      gload_lds16(Bt + (size_t)(bn * 64 + row) * K + kt * 64 + csrc,
                  (char*)Bs + (wid * 16 + j * 8) * 128);
    }
    __syncthreads();
#pragma unroll
    for (int kk = 0; kk < 2; ++kk) {
      bf16x8 a[4], b[2];
#pragma unroll
      for (int ms = 0; ms < 4; ++ms) {
        int row = wm * 64 + ms * 16 + l15;
        a[ms] = *(const bf16x8*)((char*)As + row * 128 + (((kk * 4 + l4) ^ (row & 7)) * 16));
      }
#pragma unroll
      for (int ns = 0; ns < 2; ++ns) {
        int row = wn * 32 + ns * 16 + l15;
        b[ns] = *(const bf16x8*)((char*)Bs + row * 128 + (((kk * 4 + l4) ^ (row & 7)) * 16));
      }
#pragma unroll
      for (int ms = 0; ms < 4; ++ms)
#pragma unroll
        for (int ns = 0; ns < 2; ++ns)
          acc[ms][ns] = __builtin_amdgcn_mfma_f32_16x16x32_bf16(a[ms], b[ns], acc[ms][ns], 0, 0, 0);
    }
  }
#pragma unroll
  for (int ms = 0; ms < 4; ++ms) {
#pragma unroll
    for (int ns = 0; ns < 2; ++ns) {
      int n = bn * 64 + wn * 32 + ns * 16 + l15;
      float bias = b0[n];
#pragma unroll
      for (int i = 0; i < 4; ++i) {
        int m = bm * 128 + wm * 64 + ms * 16 + l4 * 4 + i;
        Cout[(size_t)m * N + n] = acc[ms][ns][i] + bias;
      }
    }
  }
}

// ---------- flash attention (R12/R14 kernel, verbatim: converged 53.6 us) ----
__global__ void __launch_bounds__(256, 2)
k_attn(const __bf16* __restrict__ qkv, const __bf16* __restrict__ kvf,
       __bf16* __restrict__ Aout) {
  __shared__ __align__(16) char smem[33792];  // merge only: 4x8KB o-slots + 1KB sums
  const int t = threadIdx.x, w = t >> 6, lane = t & 63;
  const int qpair = w & 1, half = w >> 1;
  const int l31 = lane & 31, hi = lane >> 5;
  const int f = blockIdx.x;
  const int qt = (f >> 3) & 15;               // 16 q-tiles of 128 rows
  const int bh = (f & 7) + 8 * (f >> 7);      // XCD-local heads (4 heads/XCD)
  const int b = bh >> 4, h = bh & 15;

  const char* kvbase = (const char*)kvf + (size_t)(bh * 64 + half * 32) * 8192 + lane * 16;

  bf16x8 aqA[4], aqB[4];
  {
    int qrow = b * 2048 + qt * 128 + qpair * 64 + l31;
    const __bf16* qp = qkv + (size_t)qrow * 3072 + h * 64 + hi * 8;
#pragma unroll
    for (int d = 0; d < 4; ++d) aqA[d] = *(const bf16x8*)(qp + d * 16);
    qp += (size_t)32 * 3072;
#pragma unroll
    for (int d = 0; d < 4; ++d) aqB[d] = *(const bf16x8*)(qp + d * 16);
  }

  f32x16 oA[2] = {}, oB[2] = {};
  float lsA = 0.f, lsB = 0.f;

  bf16x8 kA[4], vA[4], kB[4], vB[4];

  auto LOAD = [&](bf16x8* kf, bf16x8* vf, int tl) {
    const char* p = kvbase + (size_t)tl * 8192;
#pragma unroll
    for (int i = 0; i < 4; ++i) kf[i] = *(const bf16x8*)(p + i * 1024);
#pragma unroll
    for (int i = 0; i < 4; ++i) vf[i] = *(const bf16x8*)(p + 4096 + i * 1024);
  };

  auto BODY = [&](const bf16x8* kf, const bf16x8* vf, const bf16x8* aq,
                  f32x16* o, float& lsum) {
    f32x16 s;
    s = 0.f;
    __builtin_amdgcn_s_setprio(1);
#pragma unroll
    for (int d = 0; d < 4; ++d)
      s = __builtin_amdgcn_mfma_f32_32x32x16_bf16(kf[d], aq[d], s, 0, 0, 0);
    __builtin_amdgcn_s_setprio(0);

#pragma unroll
    for (int r = 0; r < 16; ++r) s[r] = fast_exp2(s[r]);

    float u[8];
#pragma unroll
    for (int c = 0; c < 8; ++c) u[c] = s[2 * c] + s[2 * c + 1];
#pragma unroll
    for (int st = 4; st > 0; st >>= 1)
#pragma unroll
      for (int c = 0; c < st; ++c) u[c] += u[c + st];
    lsum += u[0];

    uint32_t W[8];
#pragma unroll
    for (int c = 0; c < 8; ++c) W[c] = pack_bf2(s[2 * c], s[2 * c + 1]);

    bf16x8 pa[2];
#pragma unroll
    for (int kstep = 0; kstep < 2; ++kstep) {
      const int base = 4 * kstep;
      uint32_t w0 = W[base + 0], w1 = W[base + 1];
      uint32_t w2 = W[base + 2], w3 = W[base + 3];
      uint32_t x0 = __shfl_xor((int)w0, 32);
      uint32_t x1 = __shfl_xor((int)w1, 32);
      uint32_t x2 = __shfl_xor((int)w2, 32);
      uint32_t x3 = __shfl_xor((int)w3, 32);
      i32x4 pw;
      pw[0] = (int)(hi ? x2 : w0);
      pw[1] = (int)(hi ? x3 : w1);
      pw[2] = (int)(hi ? w2 : x0);
      pw[3] = (int)(hi ? w3 : x1);
      pa[kstep] = __builtin_bit_cast(bf16x8, pw);
    }

    __builtin_amdgcn_s_setprio(1);
#pragma unroll
    for (int kstep = 0; kstep < 2; ++kstep)
#pragma unroll
      for (int db = 0; db < 2; ++db)
        o[db] = __builtin_amdgcn_mfma_f32_32x32x16_bf16(pa[kstep], vf[kstep * 2 + db], o[db], 0, 0, 0);
    __builtin_amdgcn_s_setprio(0);
  };

  LOAD(kA, vA, 0);
  for (int tl = 0; tl < 32; tl += 2) {
    LOAD(kB, vB, tl + 1);
    BODY(kA, vA, aqA, oA, lsA);
    BODY(kA, vA, aqB, oB, lsB);
    if (tl + 2 < 32) LOAD(kA, vA, tl + 2);
    BODY(kB, vB, aqA, oA, lsA);
    BODY(kB, vB, aqB, oB, lsB);
  }

  lsA += __shfl_xor(lsA, 32);
  lsB += __shfl_xor(lsB, 32);

  float* oLDS = (float*)smem;
  float* sLDS = (float*)(smem + 32768);
  if (half == 1) {
    float* obA = oLDS + (qpair * 2 + 0) * 2048;
    float* obB = oLDS + (qpair * 2 + 1) * 2048;
#pragma unroll
    for (int db = 0; db < 2; ++db)
#pragma unroll
      for (int r = 0; r < 16; ++r) {
        obA[(db * 16 + r) * 64 + lane] = oA[db][r];
        obB[(db * 16 + r) * 64 + lane] = oB[db][r];
      }
    sLDS[(qpair * 2 + 0) * 64 + lane] = lsA;
    sLDS[(qpair * 2 + 1) * 64 + lane] = lsB;
  }
  __syncthreads();
  if (half == 0) {
    const float* obA = oLDS + (qpair * 2 + 0) * 2048;
    const float* obB = oLDS + (qpair * 2 + 1) * 2048;
#pragma unroll
    for (int db = 0; db < 2; ++db)
#pragma unroll
      for (int r = 0; r < 16; ++r) {
        oA[db][r] += obA[(db * 16 + r) * 64 + lane];
        oB[db][r] += obB[(db * 16 + r) * 64 + lane];
      }
    lsA += sLDS[(qpair * 2 + 0) * 64 + lane];
    lsB += sLDS[(qpair * 2 + 1) * 64 + lane];

    int qbase = b * 2048 + qt * 128 + qpair * 64;
#pragma unroll
    for (int r = 0; r < 16; ++r) {
      int rowq = (r & 3) + 8 * (r >> 2) + 4 * hi;
      float invA = 1.0f / __shfl(lsA, rowq);
      float invB = 1.0f / __shfl(lsB, rowq);
#pragma unroll
      for (int db = 0; db < 2; ++db) {
        int col = h * 64 + db * 32 + l31;
        Aout[(size_t)(qbase + rowq) * 1024 + col]      = (__bf16)(oA[db][r] * invA);
        Aout[(size_t)(qbase + 32 + rowq) * 1024 + col] = (__bf16)(oB[db][r] * invB);
      }
    }
  }
}

// ---------- launch ----------
extern "C" void kernel_launch(void* const* d_in, const int* in_sizes, int n_in,
                              void* d_out, int out_size, void* d_ws, size_t ws_size,
                              hipStream_t stream) {
  const float* x  = (const float*)d_in[0];
  const float* Wq = (const float*)d_in[1];
  const float* bq = (const float*)d_in[2];
  const float* Wk = (const float*)d_in[3];
  const float* bk = (const float*)d_in[4];
  const float* Wv = (const float*)d_in[5];
  const float* bv = (const float*)d_in[6];
  const float* Wo = (const float*)d_in[7];
  const float* bo = (const float*)d_in[8];
  float* out = (float*)d_out;

  char* ws = (char*)d_ws;
  __bf16* xf   = (__bf16*)(ws);                       // 8 MiB [0,8): x fragments (dead after GEMM0)
  __bf16* aout = (__bf16*)(ws);                       // reuses [0,8) after GEMM0
  __bf16* wf   = (__bf16*)(ws + (8ull  << 20));       // 6 MiB  [8,14): Wqkv fragments
  __bf16* wot  = (__bf16*)(ws + (14ull << 20));       // 2 MiB  [14,16)
  __bf16* qkv  = (__bf16*)(ws + (16ull << 20));       // 24 MiB [16,40): Q|.|V (K region dead)
  __bf16* kvf  = (__bf16*)(ws + (40ull << 20));       // 16 MiB [40,56): fragment-packed KV

  k_prep<<<dim3(16, 16, 12), 256, 0, stream>>>(x, xf, Wq, Wk, Wv, Wo, wf, wot);

  k_gemm0<<<dim3(768), 256, 0, stream>>>(xf, wf, qkv, kvf, bq, bk, bv);

  k_vt<<<dim3(32, 32), 256, 0, stream>>>(qkv, kvf);

  k_attn<<<dim3(512), 256, 0, stream>>>(qkv, kvf, aout);

  k_gemm1<<<dim3(16, 32), 256, 0, stream>>>(aout, wot, out, 4096, 1024, 1024, bo);
}

// Round 19
// 109.995 us; speedup vs baseline: 1.3101x; 1.3101x over previous
//
#include <hip/hip_runtime.h>
#include <stdint.h>

// ---------- types ----------
typedef __attribute__((ext_vector_type(8)))  __bf16 bf16x8;
typedef __attribute__((ext_vector_type(4)))  __bf16 bf16x4;
typedef __attribute__((ext_vector_type(4)))  float  f32x4;
typedef __attribute__((ext_vector_type(16))) float  f32x16;
typedef __attribute__((ext_vector_type(4)))  int    i32x4;

#define DEV static __device__ __forceinline__

DEV float fast_exp2(float x) {
#if __has_builtin(__builtin_amdgcn_exp2f)
  return __builtin_amdgcn_exp2f(x);
#else
  return exp2f(x);
#endif
}

// pack two f32 -> one u32 of 2x bf16 (lo = a, hi = b), RNE via (__bf16) cast
DEV uint32_t pack_bf2(float a, float b) {
  __bf16 x = (__bf16)a, y = (__bf16)b;
  uint16_t xu = __builtin_bit_cast(uint16_t, x);
  uint16_t yu = __builtin_bit_cast(uint16_t, y);
  return (uint32_t)xu | ((uint32_t)yu << 16);
}

// async global->LDS, 16B per lane; LDS dest = wave-uniform base + lane*16
DEV void gload_lds16(const void* g, void* l) {
  __builtin_amdgcn_global_load_lds(
      (const __attribute__((address_space(1))) void*)(uintptr_t)(g),
      (__attribute__((address_space(3))) void*)(uint32_t)(uintptr_t)(l),
      16, 0, 0);
}

// softmax scale folded into Q at GEMM0 epilogue: C = log2(e)/8
#define SM_SCALE 0.18033688f

// ---------- fused prep: W transposes (z<4) + x convert (z>=4) ----------
__global__ void k_prep(const float* __restrict__ x,  __bf16* __restrict__ xb,
                       const float* __restrict__ Wq, const float* __restrict__ Wk,
                       const float* __restrict__ Wv, const float* __restrict__ Wo,
                       __bf16* __restrict__ wtq, __bf16* __restrict__ wot) {
  const int z = blockIdx.z;
  if (z < 4) {
    const float* W  = (z == 0) ? Wq : (z == 1) ? Wk : (z == 2) ? Wv : Wo;
    __bf16*      Wt = (z == 3) ? wot : (wtq + (size_t)z * 1024 * 1024);
    __shared__ __bf16 T[64][66];
    int t = threadIdx.x;
    int r = t >> 2;            // 0..63
    int cq = (t & 3) << 4;     // 0,16,32,48
    {
      int gk = blockIdx.y * 64 + r;
      int gn0 = blockIdx.x * 64 + cq;
      const float* src = W + (size_t)gk * 1024 + gn0;
#pragma unroll
      for (int j = 0; j < 16; j += 4) {
        f32x4 v = *(const f32x4*)(src + j);
#pragma unroll
        for (int jj = 0; jj < 4; ++jj) T[r][cq + j + jj] = (__bf16)v[jj];
      }
    }
    __syncthreads();
    {
      int gn = blockIdx.x * 64 + r;
      int gk0 = blockIdx.y * 64 + cq;
      __bf16* dst = Wt + (size_t)gn * 1024 + gk0;
      bf16x8 o0, o1;
#pragma unroll
      for (int j = 0; j < 8; ++j) { o0[j] = T[cq + j][r]; o1[j] = T[cq + 8 + j][r]; }
      *(bf16x8*)dst = o0;
      *(bf16x8*)(dst + 8) = o1;
    }
  } else {
    int lb = (z - 4) * 256 + blockIdx.y * 16 + blockIdx.x;
    int i = (lb * 256 + (int)threadIdx.x) * 4;
    if (i < 4096 * 1024) {
      f32x4 v = *(const f32x4*)(x + i);
      bf16x4 o;
      o[0] = (__bf16)v[0]; o[1] = (__bf16)v[1];
      o[2] = (__bf16)v[2]; o[3] = (__bf16)v[3];
      *(bf16x4*)(xb + i) = o;
    }
  }
}

// ---------- GEMM0 (verified m97 structure, 128x128 tile, XCD-swizzled grid) ----
// Epilogue fusion: K-column blocks (bn 8..16) and V-column blocks (bn 16..24)
// write kvf K/V fragments DIRECTLY (bit-identical to the old k_vt copies);
// Q blocks write row-major qkv * SM_SCALE. k_vt kernel is eliminated.
__global__ void k_gemm0(const __bf16* __restrict__ A, const __bf16* __restrict__ Bt,
                        __bf16* __restrict__ Cout, __bf16* __restrict__ kvf,
                        int M, int N, int K,
                        const float* __restrict__ b0, const float* __restrict__ b1,
                        const float* __restrict__ b2) {
  __shared__ __align__(16) __bf16 As[128 * 64];
  __shared__ __align__(16) __bf16 Bs[128 * 64];
  const int t = threadIdx.x, wid = t >> 6, lane = t & 63;
  const int f = blockIdx.x;
  const int xcd = f & 7, i = f >> 3;            // i in [0,96)
  const int bm = (xcd & 3) * 8 + (i & 7);       // [0,32)
  const int bn = (xcd >> 2) * 12 + (i >> 3);    // [0,24)
  const int wm = wid >> 1, wn = wid & 1;
  const int l15 = lane & 15, l4 = lane >> 4;
  const int rr = lane >> 3, cc = lane & 7;
  f32x4 acc[4][4] = {};
  const int nk = K >> 6;
  for (int kt = 0; kt < nk; ++kt) {
    __syncthreads();
#pragma unroll
    for (int j = 0; j < 4; ++j) {
      int row = wid * 32 + j * 8 + rr;
      int csrc = (cc ^ (row & 7)) * 8;
      gload_lds16(A + (size_t)(bm * 128 + row) * K + kt * 64 + csrc,
                  (char*)As + (wid * 32 + j * 8) * 128);
      gload_lds16(Bt + (size_t)(bn * 128 + row) * K + kt * 64 + csrc,
                  (char*)Bs + (wid * 32 + j * 8) * 128);
    }
    __syncthreads();
#pragma unroll
    for (int kk = 0; kk < 2; ++kk) {
      bf16x8 a[4], b[4];
#pragma unroll
      for (int ms = 0; ms < 4; ++ms) {
        int row = wm * 64 + ms * 16 + l15;
        a[ms] = *(const bf16x8*)((char*)As + row * 128 + (((kk * 4 + l4) ^ (row & 7)) * 16));
      }
#pragma unroll
      for (int ns = 0; ns < 4; ++ns) {
        int row = wn * 64 + ns * 16 + l15;
        b[ns] = *(const bf16x8*)((char*)Bs + row * 128 + (((kk * 4 + l4) ^ (row & 7)) * 16));
      }
#pragma unroll
      for (int ms = 0; ms < 4; ++ms)
#pragma unroll
        for (int ns = 0; ns < 4; ++ns)
          acc[ms][ns] = __builtin_amdgcn_mfma_f32_16x16x32_bf16(a[ms], b[ns], acc[ms][ns], 0, 0, 0);
    }
  }
  const bool kblock = (bn >= 8 && bn < 16);
  const bool vblock = (bn >= 16);
#pragma unroll
  for (int ms = 0; ms < 4; ++ms) {
#pragma unroll
    for (int ns = 0; ns < 4; ++ns) {
      int n = bn * 128 + wn * 64 + ns * 16 + l15;
      const float* bp = (n < 1024) ? b0 : ((n < 2048) ? b1 : b2);
      float bias = bp[n & 1023];
#pragma unroll
      for (int i2 = 0; i2 < 4; ++i2) {
        int m = bm * 128 + wm * 64 + ms * 16 + l4 * 4 + i2;
        float v = acc[ms][ns][i2] + bias;
        if (kblock) {
          // K fragment write: K slot d, lane: K[tile*32+r32][d*16 + hi*8 + ...]
          int dfull = n - 1024;
          int h = dfull >> 6, d = dfull & 63;
          int bb = m >> 11, mr = m & 2047;
          int tile = mr >> 5, r32 = mr & 31;
          int lanep = r32 + ((d >> 3) & 1) * 32;
          kvf[(size_t)((bb * 16 + h) * 64 + tile) * 4096 +
              (d >> 4) * 512 + lanep * 8 + (d & 7)] = (__bf16)v;
        } else if (vblock) {
          // V fragment write: V slot s, lane: V^T[(s&1)*32+(l&31)][tile*32+((s>>1)*2+(l>>5))*8+j]
          int dfull = n - 2048;
          int h = dfull >> 6, dloc = dfull & 63;
          int bb = m >> 11, mr = m & 2047;
          int tile = mr >> 5, r32 = mr & 31;
          int koff = r32 >> 3, j = r32 & 7;
          int slot = ((koff >> 1) << 1) | (dloc >> 5);
          int lanep = (dloc & 31) + 32 * (koff & 1);
          kvf[(size_t)((bb * 16 + h) * 64 + tile) * 4096 + 2048 +
              slot * 512 + lanep * 8 + j] = (__bf16)v;
        } else {
          Cout[(size_t)m * N + n] = (__bf16)(v * SM_SCALE);  // Q, scale folded
        }
      }
    }
  }
}

// ---------- GEMM1: 128x64 tile, 4 waves of 64x32 ----------
__global__ void k_gemm1(const __bf16* __restrict__ A, const __bf16* __restrict__ Bt,
                        float* __restrict__ Cout, int M, int N, int K,
                        const float* __restrict__ b0) {
  __shared__ __align__(16) __bf16 As[128 * 64];  // 16 KB
  __shared__ __align__(16) __bf16 Bs[64 * 64];   // 8 KB
  const int t = threadIdx.x, wid = t >> 6, lane = t & 63;
  const int bm = blockIdx.y, bn = blockIdx.x;
  const int wm = wid >> 1, wn = wid & 1;
  const int l15 = lane & 15, l4 = lane >> 4;
  const int rr = lane >> 3, cc = lane & 7;
  f32x4 acc[4][2] = {};
  const int nk = K >> 6;
  for (int kt = 0; kt < nk; ++kt) {
    __syncthreads();
#pragma unroll
    for (int j = 0; j < 4; ++j) {
      int row = wid * 32 + j * 8 + rr;
      int csrc = (cc ^ (row & 7)) * 8;
      gload_lds16(A + (size_t)(bm * 128 + row) * K + kt * 64 + csrc,
                  (char*)As + (wid * 32 + j * 8) * 128);
    }
#pragma unroll
    for (int j = 0; j < 2; ++j) {
      int row = wid * 16 + j * 8 + rr;
      int csrc = (cc ^ (row & 7)) * 8;
      gload_lds16(Bt + (size_t)(bn * 64 + row) * K + kt * 64 + csrc,
                  (char*)Bs + (wid * 16 + j * 8) * 128);
    }
    __syncthreads();
#pragma unroll
    for (int kk = 0; kk < 2; ++kk) {
      bf16x8 a[4], b[2];
#pragma unroll
      for (int ms = 0; ms < 4; ++ms) {
        int row = wm * 64 + ms * 16 + l15;
        a[ms] = *(const bf16x8*)((char*)As + row * 128 + (((kk * 4 + l4) ^ (row & 7)) * 16));
      }
#pragma unroll
      for (int ns = 0; ns < 2; ++ns) {
        int row = wn * 32 + ns * 16 + l15;
        b[ns] = *(const bf16x8*)((char*)Bs + row * 128 + (((kk * 4 + l4) ^ (row & 7)) * 16));
      }
#pragma unroll
      for (int ms = 0; ms < 4; ++ms)
#pragma unroll
        for (int ns = 0; ns < 2; ++ns)
          acc[ms][ns] = __builtin_amdgcn_mfma_f32_16x16x32_bf16(a[ms], b[ns], acc[ms][ns], 0, 0, 0);
    }
  }
#pragma unroll
  for (int ms = 0; ms < 4; ++ms) {
#pragma unroll
    for (int ns = 0; ns < 2; ++ns) {
      int n = bn * 64 + wn * 32 + ns * 16 + l15;
      float bias = b0[n];
#pragma unroll
      for (int i = 0; i < 4; ++i) {
        int m = bm * 128 + wm * 64 + ms * 16 + l4 * 4 + i;
        Cout[(size_t)m * N + n] = acc[ms][ns][i] + bias;
      }
    }
  }
}

// ---------- flash attention (R12/R14 kernel, verbatim: converged 53.6 us) ----
__global__ void __launch_bounds__(256, 2)
k_attn(const __bf16* __restrict__ qkv, const __bf16* __restrict__ kvf,
       __bf16* __restrict__ Aout) {
  __shared__ __align__(16) char smem[33792];  // merge only: 4x8KB o-slots + 1KB sums
  const int t = threadIdx.x, w = t >> 6, lane = t & 63;
  const int qpair = w & 1, half = w >> 1;
  const int l31 = lane & 31, hi = lane >> 5;
  const int f = blockIdx.x;
  const int qt = (f >> 3) & 15;               // 16 q-tiles of 128 rows
  const int bh = (f & 7) + 8 * (f >> 7);      // XCD-local heads (4 heads/XCD)
  const int b = bh >> 4, h = bh & 15;

  const char* kvbase = (const char*)kvf + (size_t)(bh * 64 + half * 32) * 8192 + lane * 16;

  bf16x8 aqA[4], aqB[4];
  {
    int qrow = b * 2048 + qt * 128 + qpair * 64 + l31;
    const __bf16* qp = qkv + (size_t)qrow * 3072 + h * 64 + hi * 8;
#pragma unroll
    for (int d = 0; d < 4; ++d) aqA[d] = *(const bf16x8*)(qp + d * 16);
    qp += (size_t)32 * 3072;
#pragma unroll
    for (int d = 0; d < 4; ++d) aqB[d] = *(const bf16x8*)(qp + d * 16);
  }

  f32x16 oA[2] = {}, oB[2] = {};
  float lsA = 0.f, lsB = 0.f;

  bf16x8 kA[4], vA[4], kB[4], vB[4];

  auto LOAD = [&](bf16x8* kf, bf16x8* vf, int tl) {
    const char* p = kvbase + (size_t)tl * 8192;
#pragma unroll
    for (int i = 0; i < 4; ++i) kf[i] = *(const bf16x8*)(p + i * 1024);
#pragma unroll
    for (int i = 0; i < 4; ++i) vf[i] = *(const bf16x8*)(p + 4096 + i * 1024);
  };

  auto BODY = [&](const bf16x8* kf, const bf16x8* vf, const bf16x8* aq,
                  f32x16* o, float& lsum) {
    f32x16 s;
    s = 0.f;
    __builtin_amdgcn_s_setprio(1);
#pragma unroll
    for (int d = 0; d < 4; ++d)
      s = __builtin_amdgcn_mfma_f32_32x32x16_bf16(kf[d], aq[d], s, 0, 0, 0);
    __builtin_amdgcn_s_setprio(0);

#pragma unroll
    for (int r = 0; r < 16; ++r) s[r] = fast_exp2(s[r]);

    float u[8];
#pragma unroll
    for (int c = 0; c < 8; ++c) u[c] = s[2 * c] + s[2 * c + 1];
#pragma unroll
    for (int st = 4; st > 0; st >>= 1)
#pragma unroll
      for (int c = 0; c < st; ++c) u[c] += u[c + st];
    lsum += u[0];

    uint32_t W[8];
#pragma unroll
    for (int c = 0; c < 8; ++c) W[c] = pack_bf2(s[2 * c], s[2 * c + 1]);

    bf16x8 pa[2];
#pragma unroll
    for (int kstep = 0; kstep < 2; ++kstep) {
      const int base = 4 * kstep;
      uint32_t w0 = W[base + 0], w1 = W[base + 1];
      uint32_t w2 = W[base + 2], w3 = W[base + 3];
      uint32_t x0 = __shfl_xor((int)w0, 32);
      uint32_t x1 = __shfl_xor((int)w1, 32);
      uint32_t x2 = __shfl_xor((int)w2, 32);
      uint32_t x3 = __shfl_xor((int)w3, 32);
      i32x4 pw;
      pw[0] = (int)(hi ? x2 : w0);
      pw[1] = (int)(hi ? x3 : w1);
      pw[2] = (int)(hi ? w2 : x0);
      pw[3] = (int)(hi ? w3 : x1);
      pa[kstep] = __builtin_bit_cast(bf16x8, pw);
    }

    __builtin_amdgcn_s_setprio(1);
#pragma unroll
    for (int kstep = 0; kstep < 2; ++kstep)
#pragma unroll
      for (int db = 0; db < 2; ++db)
        o[db] = __builtin_amdgcn_mfma_f32_32x32x16_bf16(pa[kstep], vf[kstep * 2 + db], o[db], 0, 0, 0);
    __builtin_amdgcn_s_setprio(0);
  };

  LOAD(kA, vA, 0);
  for (int tl = 0; tl < 32; tl += 2) {
    LOAD(kB, vB, tl + 1);
    BODY(kA, vA, aqA, oA, lsA);
    BODY(kA, vA, aqB, oB, lsB);
    if (tl + 2 < 32) LOAD(kA, vA, tl + 2);
    BODY(kB, vB, aqA, oA, lsA);
    BODY(kB, vB, aqB, oB, lsB);
  }

  lsA += __shfl_xor(lsA, 32);
  lsB += __shfl_xor(lsB, 32);

  float* oLDS = (float*)smem;
  float* sLDS = (float*)(smem + 32768);
  if (half == 1) {
    float* obA = oLDS + (qpair * 2 + 0) * 2048;
    float* obB = oLDS + (qpair * 2 + 1) * 2048;
#pragma unroll
    for (int db = 0; db < 2; ++db)
#pragma unroll
      for (int r = 0; r < 16; ++r) {
        obA[(db * 16 + r) * 64 + lane] = oA[db][r];
        obB[(db * 16 + r) * 64 + lane] = oB[db][r];
      }
    sLDS[(qpair * 2 + 0) * 64 + lane] = lsA;
    sLDS[(qpair * 2 + 1) * 64 + lane] = lsB;
  }
  __syncthreads();
  if (half == 0) {
    const float* obA = oLDS + (qpair * 2 + 0) * 2048;
    const float* obB = oLDS + (qpair * 2 + 1) * 2048;
#pragma unroll
    for (int db = 0; db < 2; ++db)
#pragma unroll
      for (int r = 0; r < 16; ++r) {
        oA[db][r] += obA[(db * 16 + r) * 64 + lane];
        oB[db][r] += obB[(db * 16 + r) * 64 + lane];
      }
    lsA += sLDS[(qpair * 2 + 0) * 64 + lane];
    lsB += sLDS[(qpair * 2 + 1) * 64 + lane];

    int qbase = b * 2048 + qt * 128 + qpair * 64;
#pragma unroll
    for (int r = 0; r < 16; ++r) {
      int rowq = (r & 3) + 8 * (r >> 2) + 4 * hi;
      float invA = 1.0f / __shfl(lsA, rowq);
      float invB = 1.0f / __shfl(lsB, rowq);
#pragma unroll
      for (int db = 0; db < 2; ++db) {
        int col = h * 64 + db * 32 + l31;
        Aout[(size_t)(qbase + rowq) * 1024 + col]      = (__bf16)(oA[db][r] * invA);
        Aout[(size_t)(qbase + 32 + rowq) * 1024 + col] = (__bf16)(oB[db][r] * invB);
      }
    }
  }
}

// ---------- launch ----------
extern "C" void kernel_launch(void* const* d_in, const int* in_sizes, int n_in,
                              void* d_out, int out_size, void* d_ws, size_t ws_size,
                              hipStream_t stream) {
  const float* x  = (const float*)d_in[0];
  const float* Wq = (const float*)d_in[1];
  const float* bq = (const float*)d_in[2];
  const float* Wk = (const float*)d_in[3];
  const float* bk = (const float*)d_in[4];
  const float* Wv = (const float*)d_in[5];
  const float* bv = (const float*)d_in[6];
  const float* Wo = (const float*)d_in[7];
  const float* bo = (const float*)d_in[8];
  float* out = (float*)d_out;

  char* ws = (char*)d_ws;
  __bf16* xb   = (__bf16*)(ws);                       // 8 MiB [0,8): x bf16 (dead after GEMM0)
  __bf16* aout = (__bf16*)(ws);                       // reuses [0,8) after GEMM0
  __bf16* wtq  = (__bf16*)(ws + (8ull  << 20));       // 6 MiB  [8,14)
  __bf16* wot  = (__bf16*)(ws + (14ull << 20));       // 2 MiB  [14,16)
  __bf16* qkv  = (__bf16*)(ws + (16ull << 20));       // 24 MiB [16,40): Q only (stride 3072)
  __bf16* kvf  = (__bf16*)(ws + (40ull << 20));       // 16 MiB [40,56): fragment-packed KV

  k_prep<<<dim3(16, 16, 20), 256, 0, stream>>>(x, xb, Wq, Wk, Wv, Wo, wtq, wot);

  k_gemm0<<<dim3(768), 256, 0, stream>>>(xb, wtq, qkv, kvf, 4096, 3072, 1024, bq, bk, bv);

  k_attn<<<dim3(512), 256, 0, stream>>>(qkv, kvf, aout);

  k_gemm1<<<dim3(16, 32), 256, 0, stream>>>(aout, wot, out, 4096, 1024, 1024, bo);
}